// Round 2
// baseline (18.653 us; speedup 1.0000x reference)
//
#include <hip/hip_runtime.h>

// One 64-lane wave per block (wave id == blockIdx.x -> provably uniform ->
// scalar s_load for indices/biases). Each wave handles EPW=4 batch elements:
// 4 independent gather chains in flight, interleaved shfl-xor reductions.
constexpr int EPW = 4;

__global__ __launch_bounds__(64) void hist_mf_kernel(
    const int*   __restrict__ users,
    const int*   __restrict__ items,
    const int*   __restrict__ item_pos,
    const float* __restrict__ ratings,
    const float* __restrict__ user_factors,
    const float* __restrict__ item_factors,
    const float* __restrict__ user_biases,
    const float* __restrict__ item_biases,
    const int*   __restrict__ minr_p,
    const int*   __restrict__ maxr_p,
    int L, int F, int B,
    float* __restrict__ out)
{
    const int w    = blockIdx.x;       // uniform
    const int lane = threadIdx.x;      // 0..63
    const int e0   = w * EPW;
    if (e0 >= B) return;

    const int minr = *minr_p, maxr = *maxr_p;
    const int bins = maxr;
    const float fmin  = (float)minr;
    const float fmax  = (float)maxr;
    const float width = (float)(maxr - minr) / (float)bins;
    const float invw  = 1.0f / width;
    const float lo    = (float)((minr - 1) > 0 ? minr - 1 : 0);
    const float hi    = (float)(maxr - 1);

    // ---- scalar index loads (uniform: e is blockIdx-derived) ----
    int u[EPW], it[EPW], ps[EPW];
    #pragma unroll
    for (int k = 0; k < EPW; ++k) {
        int e = min(e0 + k, B - 1);
        u[k]  = users[e];
        it[k] = items[e];
        ps[k] = item_pos[e];
    }

    // ---- issue ratings-row loads early (1 float4/lane per element) ----
    const float* rowp[EPW];
    #pragma unroll
    for (int k = 0; k < EPW; ++k) rowp[k] = ratings + (size_t)u[k] * L;

    const int nchunk = ((L & 3) == 0) ? (L >> 8) : 0;  // 256-float chunks
    float4 r4[EPW];
    #pragma unroll
    for (int k = 0; k < EPW; ++k)
        r4[k] = (nchunk > 0) ? reinterpret_cast<const float4*>(rowp[k])[lane]
                             : make_float4(0.f, 0.f, 0.f, 0.f);

    // ---- dot products (F==64: one element/lane), 4 chains interleaved ----
    float d[EPW];
    #pragma unroll
    for (int k = 0; k < EPW; ++k) d[k] = 0.f;
    for (int f = lane; f < F; f += 64) {
        #pragma unroll
        for (int k = 0; k < EPW; ++k)
            d[k] += user_factors[(size_t)u[k] * F + f] *
                    item_factors[(size_t)it[k] * F + f];
    }
    #pragma unroll
    for (int o = 32; o > 0; o >>= 1) {
        #pragma unroll
        for (int k = 0; k < EPW; ++k) d[k] += __shfl_xor(d[k], o, 64);
    }

    float pred[EPW], endv[EPW], mass[EPW];
    #pragma unroll
    for (int k = 0; k < EPW; ++k) {
        pred[k] = user_biases[u[k]] + item_biases[it[k]] + d[k];  // scalar bias loads
        endv[k] = fminf(fmaxf(rintf(pred[k]), lo), hi);
        mass[k] = 0.f;
    }

    // ---- histogram mass ----
    auto accum = [&](float rraw, int j, int pos, float predv, float ev, float& m) {
        float v = (j == pos) ? predv : rraw;
        bool in = (v >= fmin) && (v <= fmax);
        float fidx = floorf((v - fmin) * invw);
        if (v == fmax) fidx = (float)(bins - 1);
        if (in) {
            if (fidx <= ev) m += 1.0f;
            if (fidx == ev) m -= 0.5f;
        }
    };

    if (nchunk > 0) {
        const int j0 = lane * 4;
        #pragma unroll
        for (int k = 0; k < EPW; ++k) {
            accum(r4[k].x, j0 + 0, ps[k], pred[k], endv[k], mass[k]);
            accum(r4[k].y, j0 + 1, ps[k], pred[k], endv[k], mass[k]);
            accum(r4[k].z, j0 + 2, ps[k], pred[k], endv[k], mass[k]);
            accum(r4[k].w, j0 + 3, ps[k], pred[k], endv[k], mass[k]);
        }
    }
    for (int c = 1; c < nchunk; ++c) {
        const int j0 = c * 256 + lane * 4;
        #pragma unroll
        for (int k = 0; k < EPW; ++k) {
            float4 q = reinterpret_cast<const float4*>(rowp[k] + c * 256)[lane];
            accum(q.x, j0 + 0, ps[k], pred[k], endv[k], mass[k]);
            accum(q.y, j0 + 1, ps[k], pred[k], endv[k], mass[k]);
            accum(q.z, j0 + 2, ps[k], pred[k], endv[k], mass[k]);
            accum(q.w, j0 + 3, ps[k], pred[k], endv[k], mass[k]);
        }
    }
    for (int j = (nchunk << 8) + lane; j < L; j += 64) {  // scalar tail
        #pragma unroll
        for (int k = 0; k < EPW; ++k)
            accum(rowp[k][j], j, ps[k], pred[k], endv[k], mass[k]);
    }

    #pragma unroll
    for (int o = 32; o > 0; o >>= 1) {
        #pragma unroll
        for (int k = 0; k < EPW; ++k) mass[k] += __shfl_xor(mass[k], o, 64);
    }

    // ---- output: lane 0 writes [pred, mass] pairs, vectorized ----
    if (lane == 0) {
        const int nv = min(EPW, B - e0);
        if (nv == EPW) {
            reinterpret_cast<float4*>(out)[2 * w + 0] =
                make_float4(pred[0], mass[0], pred[1], mass[1]);
            reinterpret_cast<float4*>(out)[2 * w + 1] =
                make_float4(pred[2], mass[2], pred[3], mass[3]);
        } else {
            for (int k = 0; k < nv; ++k) {
                out[2 * (e0 + k) + 0] = pred[k];
                out[2 * (e0 + k) + 1] = mass[k];
            }
        }
    }
}

extern "C" void kernel_launch(void* const* d_in, const int* in_sizes, int n_in,
                              void* d_out, int out_size, void* d_ws, size_t ws_size,
                              hipStream_t stream) {
    const int*   users        = (const int*)  d_in[0];
    const int*   items        = (const int*)  d_in[1];
    const int*   item_pos     = (const int*)  d_in[2];
    const float* ratings      = (const float*)d_in[3];
    const float* user_factors = (const float*)d_in[4];
    const float* item_factors = (const float*)d_in[5];
    const float* user_biases  = (const float*)d_in[6];
    const float* item_biases  = (const float*)d_in[7];
    const int*   minr_p       = (const int*)  d_in[8];
    const int*   maxr_p       = (const int*)  d_in[9];

    const int B       = in_sizes[0];
    const int N_USERS = in_sizes[6];           // user_biases is (N_USERS, 1)
    const int L       = in_sizes[3] / N_USERS; // ratings is (N_USERS, L)
    const int F       = in_sizes[4] / N_USERS; // user_factors is (N_USERS, F)

    float* out = (float*)d_out;

    const int grid = (B + EPW - 1) / EPW;      // one wave (64 threads) per block
    hist_mf_kernel<<<grid, 64, 0, stream>>>(
        users, items, item_pos, ratings, user_factors, item_factors,
        user_biases, item_biases, minr_p, maxr_p, L, F, B, out);
}